// Round 8
// baseline (69.093 us; speedup 1.0000x reference)
//
#include <hip/hip_runtime.h>
#include <hip/hip_fp16.h>

#define NG 64
#define NVOX (NG*NG*NG)
#define NC 16
#define NHID 32
#define NL 10

typedef _Float16 half8 __attribute__((ext_vector_type(8)));
typedef __fp16   fp16x2 __attribute__((ext_vector_type(2)));
typedef float f32x16 __attribute__((ext_vector_type(16)));
typedef float f32x2 __attribute__((ext_vector_type(2)));

union U32H2 { unsigned u; fp16x2 h; __half2 hh; };
union U4H8  { uint4 u; half8 v; };

__device__ __forceinline__ unsigned pkrtz(float a, float b) {
    U32H2 t; t.h = __builtin_amdgcn_cvt_pkrtz(a, b); return t.u;
}
__device__ __forceinline__ half8 mk8(unsigned a, unsigned b, unsigned c, unsigned d) {
    union { unsigned u[4]; half8 v; } r;
    r.u[0] = a; r.u[1] = b; r.u[2] = c; r.u[3] = d; return r.v;
}
__device__ __forceinline__ f32x16 MF(half8 a, half8 b, f32x16 c) {
    return __builtin_amdgcn_mfma_f32_32x32x16_f16(a, b, c, 0, 0, 0);
}
// v_permlane32_swap_b32 a,b : a <- [a_lo | b_lo], b <- [a_hi | b_hi]
#define PSWAP(a, b) asm volatile("v_permlane32_swap_b32 %0, %1" : "+v"(a), "+v"(b))

// ---- workspace layout ----
#define GRID_BYTES ((size_t)NVOX * 16)               // 4 MiB fp8 grid (uint4/voxel)
#define A0F_OFF  GRID_BYTES                           // [5][64] uint4  layer-0 A frags
#define AHF_OFF  (A0F_OFF + (size_t)5 * 64 * 16)      // [6][64] uint4  hidden A frags
#define CBF_OFF  (AHF_OFF + (size_t)6 * 64 * 16)      // [12][64] float4 bias C frags
#define WFF_OFF  (CBF_OFF + (size_t)12 * 64 * 16)     // [4][64] float4  Wf frags
#define WS_NEED  (WFF_OFF + (size_t)4 * 64 * 16)

// Per-lane MFMA weight fragments (verified construction, R4).
// x k-layout: k0,1=cx,cy k2=cz k3=1(bias) k4..63=PE k64..79=feats.
__device__ void pack_weights_lane(int lane,
    const float* __restrict__ W0, const float* __restrict__ b0,
    const float* __restrict__ Wh, const float* __restrict__ bh,
    const float* __restrict__ Wf,
    uint4* a0f, uint4* ahf, float4* cbf, float4* wff)
{
    const int H = lane >> 5, nn = lane & 31;
#pragma unroll
    for (int s = 0; s < 5; ++s) {
        float e[8];
#pragma unroll
        for (int i = 0; i < 8; ++i) {
            const int k0 = s * 16 + i;
            const float* q0 = (k0 == 3) ? (b0 + nn)
                             : (W0 + (k0 - (k0 >= 4 ? 1 : 0)) * NHID + nn);
            const float* q1 = W0 + (k0 + 8 - 1) * NHID + nn;   // k1>=8, never bias
            e[i] = *(H ? q1 : q0);
        }
        a0f[s * 64 + lane] = make_uint4(pkrtz(e[0], e[1]), pkrtz(e[2], e[3]),
                                        pkrtz(e[4], e[5]), pkrtz(e[6], e[7]));
    }
#pragma unroll
    for (int L = 0; L < 3; ++L) {
#pragma unroll
        for (int t = 0; t < 2; ++t) {
            float e[8];
#pragma unroll
            for (int i = 0; i < 8; ++i)
                e[i] = Wh[(L * NHID + t * 16 + H * 8 + i) * NHID + nn];
            ahf[(L * 2 + t) * 64 + lane] =
                make_uint4(pkrtz(e[0], e[1]), pkrtz(e[2], e[3]),
                           pkrtz(e[4], e[5]), pkrtz(e[6], e[7]));
        }
        float c[16];
#pragma unroll
        for (int r = 0; r < 16; ++r) {
            int nr = (r & 3) + 8 * (r >> 2) + 4 * H;
            c[r] = bh[L * NHID + nr];
        }
#pragma unroll
        for (int q = 0; q < 4; ++q)
            cbf[(L * 4 + q) * 64 + lane] =
                make_float4(c[4 * q], c[4 * q + 1], c[4 * q + 2], c[4 * q + 3]);
    }
    float w[16];
#pragma unroll
    for (int r = 0; r < 16; ++r) {
        int nr = (r & 3) + 8 * (r >> 2) + 4 * H;
        w[r] = Wf[nr];
    }
#pragma unroll
    for (int q = 0; q < 4; ++q)
        wff[q * 64 + lane] = make_float4(w[4 * q], w[4 * q + 1], w[4 * q + 2], w[4 * q + 3]);
}

// ---- pass 1: grid f32 (C,D,H,W) -> voxel-major fp8 e4m3; block 0 packs weights ----
__global__ __launch_bounds__(256) void prep_kernel(
    const float* __restrict__ in, uint4* __restrict__ gout,
    const float* __restrict__ W0, const float* __restrict__ b0,
    const float* __restrict__ Wh, const float* __restrict__ bh,
    const float* __restrict__ Wf,
    uint4* a0f, uint4* ahf, float4* cbf, float4* wff)
{
    int v = blockIdx.x * 256 + threadIdx.x;
    if (v < NVOX) {
        unsigned o[4];
#pragma unroll
        for (int c = 0; c < 4; ++c) {
            float f0 = in[(4 * c + 0) * NVOX + v];
            float f1 = in[(4 * c + 1) * NVOX + v];
            float f2 = in[(4 * c + 2) * NVOX + v];
            float f3 = in[(4 * c + 3) * NVOX + v];
            int w = 0;
            w = __builtin_amdgcn_cvt_pk_fp8_f32(f0, f1, w, false);
            w = __builtin_amdgcn_cvt_pk_fp8_f32(f2, f3, w, true);
            o[c] = (unsigned)w;
        }
        gout[v] = make_uint4(o[0], o[1], o[2], o[3]);
    }
    if (blockIdx.x == 0 && threadIdx.x < 64)
        pack_weights_lane(threadIdx.x, W0, b0, Wh, bh, Wf, a0f, ahf, cbf, wff);
}

// ---- pass 2: fused grid-sample + PE + 4-layer MLP, f16 MFMA, zero LDS ----
__global__ __launch_bounds__(256, 6) void fgm_mfma(
    const float* __restrict__ coords, const uint4* __restrict__ grid8,
    const uint4* __restrict__ a0f, const uint4* __restrict__ ahf,
    const float4* __restrict__ cbf, const float4* __restrict__ wff,
    const float* __restrict__ bf,
    float* __restrict__ out, int n)
{
    const int lane = threadIdx.x & 63;
    const int wid  = threadIdx.x >> 6;
    const int base = blockIdx.x * 256 + wid * 64;
    if (base >= n) return;
    const int p  = base + lane;
    const int pc = min(p, n - 1);
    const int H  = lane >> 5;

    float cx = coords[3 * pc + 0], cy = coords[3 * pc + 1], cz = coords[3 * pc + 2];

    // ---- trilinear grid sample, fp8 grid -> f32 accumulate ----
    float fx = (cx + 1.0f) * (NG * 0.5f) - 0.5f;
    float fy = (cy + 1.0f) * (NG * 0.5f) - 0.5f;
    float fz = (cz + 1.0f) * (NG * 0.5f) - 0.5f;
    float flx = floorf(fx), fly = floorf(fy), flz = floorf(fz);
    float wx = fx - flx, wy = fy - fly, wz = fz - flz;
    int ix0 = (int)flx, iy0 = (int)fly, iz0 = (int)flz;
    float wxs[2] = {1.0f - wx, wx}, wys[2] = {1.0f - wy, wy}, wzs[2] = {1.0f - wz, wz};

    float fv[NC];
#pragma unroll
    for (int c = 0; c < NC; ++c) fv[c] = 0.0f;

#pragma unroll
    for (int dz = 0; dz < 2; ++dz) {
        int zi = iz0 + dz; bool vz = (zi >= 0) && (zi < NG);
        int zc = min(max(zi, 0), NG - 1);
#pragma unroll
        for (int dy = 0; dy < 2; ++dy) {
            int yi = iy0 + dy; bool vy = (yi >= 0) && (yi < NG);
            int yc = min(max(yi, 0), NG - 1);
#pragma unroll
            for (int dx = 0; dx < 2; ++dx) {
                int xi = ix0 + dx; bool vx = (xi >= 0) && (xi < NG);
                int xc = min(max(xi, 0), NG - 1);
                float w = wzs[dz] * wys[dy] * wxs[dx];
                w = (vx && vy && vz) ? w : 0.0f;
                uint4 q = grid8[((zc * NG) + yc) * NG + xc];
                f32x2 d;
                d = __builtin_amdgcn_cvt_pk_f32_fp8((int)q.x, false);
                fv[0]  = fmaf(w, d.x, fv[0]);  fv[1]  = fmaf(w, d.y, fv[1]);
                d = __builtin_amdgcn_cvt_pk_f32_fp8((int)q.x, true);
                fv[2]  = fmaf(w, d.x, fv[2]);  fv[3]  = fmaf(w, d.y, fv[3]);
                d = __builtin_amdgcn_cvt_pk_f32_fp8((int)q.y, false);
                fv[4]  = fmaf(w, d.x, fv[4]);  fv[5]  = fmaf(w, d.y, fv[5]);
                d = __builtin_amdgcn_cvt_pk_f32_fp8((int)q.y, true);
                fv[6]  = fmaf(w, d.x, fv[6]);  fv[7]  = fmaf(w, d.y, fv[7]);
                d = __builtin_amdgcn_cvt_pk_f32_fp8((int)q.z, false);
                fv[8]  = fmaf(w, d.x, fv[8]);  fv[9]  = fmaf(w, d.y, fv[9]);
                d = __builtin_amdgcn_cvt_pk_f32_fp8((int)q.z, true);
                fv[10] = fmaf(w, d.x, fv[10]); fv[11] = fmaf(w, d.y, fv[11]);
                d = __builtin_amdgcn_cvt_pk_f32_fp8((int)q.w, false);
                fv[12] = fmaf(w, d.x, fv[12]); fv[13] = fmaf(w, d.y, fv[13]);
                d = __builtin_amdgcn_cvt_pk_f32_fp8((int)q.w, true);
                fv[14] = fmaf(w, d.x, fv[14]); fv[15] = fmaf(w, d.y, fv[15]);
            }
        }
    }

    // ---- x (f16 pairs) in registers ----
    unsigned xr[40];
    xr[0] = pkrtz(cx, cy);
    xr[1] = pkrtz(cz, 1.0f);      // k=3: bias row input = 1
#pragma unroll
    for (int l0 = 0; l0 < NL; ++l0) {
        float f = (float)(1 << l0);
        float sx, cax, sy, cay, sz, caz;
        __sincosf(cx * f, &sx, &cax);
        __sincosf(cy * f, &sy, &cay);
        __sincosf(cz * f, &sz, &caz);
        xr[2 + 3 * l0 + 0] = pkrtz(sx, sy);
        xr[2 + 3 * l0 + 1] = pkrtz(sz, cax);
        xr[2 + 3 * l0 + 2] = pkrtz(cay, caz);
    }
#pragma unroll
    for (int j = 0; j < 8; ++j)
        xr[32 + j] = pkrtz(fv[2 * j], fv[2 * j + 1]);

    // ---- layer-0 B-fragments via permlane32_swap (in place on xr) ----
#pragma unroll
    for (int s = 0; s < 5; ++s) {
        PSWAP(xr[8 * s + 0], xr[8 * s + 4]);
        PSWAP(xr[8 * s + 1], xr[8 * s + 5]);
        PSWAP(xr[8 * s + 2], xr[8 * s + 6]);
        PSWAP(xr[8 * s + 3], xr[8 * s + 7]);
    }

    // ---- layer 0: 5 K-slices x 2 tiles, prepacked A frags ----
    f32x16 acc0, acc1;
#pragma unroll
    for (int r = 0; r < 16; ++r) { acc0[r] = 0.0f; acc1[r] = 0.0f; }
#pragma unroll
    for (int s = 0; s < 5; ++s) {
        U4H8 af; af.u = a0f[s * 64 + lane];
        acc0 = MF(af.v, mk8(xr[8*s+0], xr[8*s+1], xr[8*s+2], xr[8*s+3]), acc0);
        acc1 = MF(af.v, mk8(xr[8*s+4], xr[8*s+5], xr[8*s+6], xr[8*s+7]), acc1);
    }

    // ---- hidden layers: snake -> f16 pairs -> permlane B-frags -> MFMA ----
#pragma unroll
    for (int L = 0; L < 3; ++L) {
        unsigned w0a[8], w1a[8];
#pragma unroll
        for (int j = 0; j < 8; ++j) {
            {
                float x0 = acc0[2 * j], x1 = acc0[2 * j + 1];
                float s0 = __sinf(x0), s1 = __sinf(x1);
                w0a[j] = pkrtz(fmaf(0.5f, x0, s0 * s0), fmaf(0.5f, x1, s1 * s1));
            }
            {
                float x0 = acc1[2 * j], x1 = acc1[2 * j + 1];
                float s0 = __sinf(x0), s1 = __sinf(x1);
                w1a[j] = pkrtz(fmaf(0.5f, x0, s0 * s0), fmaf(0.5f, x1, s1 * s1));
            }
        }
        PSWAP(w0a[0], w0a[2]); PSWAP(w0a[1], w0a[3]);
        PSWAP(w0a[4], w0a[6]); PSWAP(w0a[5], w0a[7]);
        PSWAP(w1a[0], w1a[2]); PSWAP(w1a[1], w1a[3]);
        PSWAP(w1a[4], w1a[6]); PSWAP(w1a[5], w1a[7]);

        float4 c0 = cbf[(L * 4 + 0) * 64 + lane];
        float4 c1 = cbf[(L * 4 + 1) * 64 + lane];
        float4 c2 = cbf[(L * 4 + 2) * 64 + lane];
        float4 c3 = cbf[(L * 4 + 3) * 64 + lane];
        f32x16 cb;
        cb[0]  = c0.x; cb[1]  = c0.y; cb[2]  = c0.z; cb[3]  = c0.w;
        cb[4]  = c1.x; cb[5]  = c1.y; cb[6]  = c1.z; cb[7]  = c1.w;
        cb[8]  = c2.x; cb[9]  = c2.y; cb[10] = c2.z; cb[11] = c2.w;
        cb[12] = c3.x; cb[13] = c3.y; cb[14] = c3.z; cb[15] = c3.w;

        U4H8 A0, A1;
        A0.u = ahf[(L * 2 + 0) * 64 + lane];
        A1.u = ahf[(L * 2 + 1) * 64 + lane];

        acc0 = MF(A1.v, mk8(w0a[4], w0a[5], w0a[6], w0a[7]),
                  MF(A0.v, mk8(w0a[0], w0a[1], w0a[2], w0a[3]), cb));
        acc1 = MF(A1.v, mk8(w1a[4], w1a[5], w1a[6], w1a[7]),
                  MF(A0.v, mk8(w1a[0], w1a[1], w1a[2], w1a[3]), cb));
    }

    // ---- final layer: snake -> dot(Wf) -> cross-half reduce ----
    float4 w0v = wff[0 * 64 + lane], w1v = wff[1 * 64 + lane];
    float4 w2v = wff[2 * 64 + lane], w3v = wff[3 * 64 + lane];
    float wfv[16] = {w0v.x, w0v.y, w0v.z, w0v.w, w1v.x, w1v.y, w1v.z, w1v.w,
                     w2v.x, w2v.y, w2v.z, w2v.w, w3v.x, w3v.y, w3v.z, w3v.w};
    float t0 = 0.0f, t1 = 0.0f;
#pragma unroll
    for (int r = 0; r < 16; ++r) {
        float wf = wfv[r];
        { float x = acc0[r]; float s = __sinf(x); t0 = fmaf(fmaf(0.5f, x, s * s), wf, t0); }
        { float x = acc1[r]; float s = __sinf(x); t1 = fmaf(fmaf(0.5f, x, s * s), wf, t1); }
    }
    t0 += __shfl_xor(t0, 32);
    t1 += __shfl_xor(t1, 32);
    float res = (H ? t1 : t0) + bf[0];
    if (p < n) out[p] = res;
}

// ---- fallback (ws too small): scalar fp32 path, channels-first grid ----
__global__ __launch_bounds__(256) void fgm_scalar(
    const float* __restrict__ coords, const float* __restrict__ grid,
    const float* __restrict__ W0, const float* __restrict__ b0,
    const float* __restrict__ Wh, const float* __restrict__ bh,
    const float* __restrict__ Wf, const float* __restrict__ bf,
    float* __restrict__ out, int n)
{
    int i = blockIdx.x * blockDim.x + threadIdx.x;
    if (i >= n) return;
    float cx = coords[3 * i + 0], cy = coords[3 * i + 1], cz = coords[3 * i + 2];
    float fx = (cx + 1.0f) * (NG * 0.5f) - 0.5f;
    float fy = (cy + 1.0f) * (NG * 0.5f) - 0.5f;
    float fz = (cz + 1.0f) * (NG * 0.5f) - 0.5f;
    float flx = floorf(fx), fly = floorf(fy), flz = floorf(fz);
    float wx = fx - flx, wy = fy - fly, wz = fz - flz;
    int ix0 = (int)flx, iy0 = (int)fly, iz0 = (int)flz;
    float fv[NC];
#pragma unroll
    for (int c = 0; c < NC; ++c) fv[c] = 0.0f;
    float wxs[2] = {1.0f - wx, wx}, wys[2] = {1.0f - wy, wy}, wzs[2] = {1.0f - wz, wz};
#pragma unroll
    for (int dz = 0; dz < 2; ++dz) {
        int zi = iz0 + dz; bool vz = (zi >= 0) && (zi < NG);
        int zc = min(max(zi, 0), NG - 1);
#pragma unroll
        for (int dy = 0; dy < 2; ++dy) {
            int yi = iy0 + dy; bool vy = (yi >= 0) && (yi < NG);
            int yc = min(max(yi, 0), NG - 1);
#pragma unroll
            for (int dx = 0; dx < 2; ++dx) {
                int xi = ix0 + dx; bool vx = (xi >= 0) && (xi < NG);
                int xc = min(max(xi, 0), NG - 1);
                float w = wzs[dz] * wys[dy] * wxs[dx];
                w = (vx && vy && vz) ? w : 0.0f;
                int off = ((zc * NG) + yc) * NG + xc;
#pragma unroll
                for (int c = 0; c < NC; ++c)
                    fv[c] = fmaf(w, grid[c * NVOX + off], fv[c]);
            }
        }
    }
    float h[NHID];
#pragma unroll
    for (int j = 0; j < NHID; ++j) h[j] = b0[j];
#pragma unroll
    for (int j = 0; j < NHID; ++j) h[j] = fmaf(cx, W0[0 * NHID + j], h[j]);
#pragma unroll
    for (int j = 0; j < NHID; ++j) h[j] = fmaf(cy, W0[1 * NHID + j], h[j]);
#pragma unroll
    for (int j = 0; j < NHID; ++j) h[j] = fmaf(cz, W0[2 * NHID + j], h[j]);
#pragma unroll
    for (int l = 0; l < NL; ++l) {
        float fs = (float)(1 << l);
        float sv[6];
        sv[0] = __sinf(cx * fs); sv[1] = __sinf(cy * fs); sv[2] = __sinf(cz * fs);
        sv[3] = __cosf(cx * fs); sv[4] = __cosf(cy * fs); sv[5] = __cosf(cz * fs);
#pragma unroll
        for (int r = 0; r < 6; ++r) {
            const float* wr = W0 + (size_t)(3 + 6 * l + r) * NHID;
            float a = sv[r];
#pragma unroll
            for (int j = 0; j < NHID; ++j) h[j] = fmaf(a, wr[j], h[j]);
        }
    }
#pragma unroll
    for (int r = 0; r < NC; ++r) {
        const float* wr = W0 + (size_t)(3 + 6 * NL + r) * NHID;
        float a = fv[r];
#pragma unroll
        for (int j = 0; j < NHID; ++j) h[j] = fmaf(a, wr[j], h[j]);
    }
    float act[NHID];
#pragma unroll
    for (int layer = 0; layer < 3; ++layer) {
#pragma unroll
        for (int j = 0; j < NHID; ++j) {
            float s = __sinf(h[j]);
            act[j] = fmaf(0.5f, h[j], s * s);
        }
#pragma unroll
        for (int j = 0; j < NHID; ++j) h[j] = bh[layer * NHID + j];
#pragma unroll
        for (int r = 0; r < NHID; ++r) {
            const float* wr = Wh + (size_t)(layer * NHID + r) * NHID;
            float a = act[r];
#pragma unroll
            for (int j = 0; j < NHID; ++j) h[j] = fmaf(a, wr[j], h[j]);
        }
    }
    float acc = bf[0];
#pragma unroll
    for (int j = 0; j < NHID; ++j) {
        float s = __sinf(h[j]);
        acc = fmaf(fmaf(0.5f, h[j], s * s), Wf[j], acc);
    }
    out[i] = acc;
}

extern "C" void kernel_launch(void* const* d_in, const int* in_sizes, int n_in,
                              void* d_out, int out_size, void* d_ws, size_t ws_size,
                              hipStream_t stream)
{
    const float* coords = (const float*)d_in[0];
    const float* grid   = (const float*)d_in[1];
    const float* W0     = (const float*)d_in[2];
    const float* b0     = (const float*)d_in[3];
    const float* Wh     = (const float*)d_in[4];
    const float* bh     = (const float*)d_in[5];
    const float* Wf     = (const float*)d_in[6];
    const float* bf     = (const float*)d_in[7];
    float* out = (float*)d_out;
    int n = in_sizes[0] / 3;

    if (ws_size >= WS_NEED) {
        char* ws = (char*)d_ws;
        uint4*  g8  = (uint4*)ws;
        uint4*  a0f = (uint4*)(ws + A0F_OFF);
        uint4*  ahf = (uint4*)(ws + AHF_OFF);
        float4* cbf = (float4*)(ws + CBF_OFF);
        float4* wff = (float4*)(ws + WFF_OFF);
        prep_kernel<<<(NVOX + 255) / 256, 256, 0, stream>>>(
            grid, g8, W0, b0, Wh, bh, Wf, a0f, ahf, cbf, wff);
        fgm_mfma<<<(n + 255) / 256, 256, 0, stream>>>(
            coords, g8, a0f, ahf, cbf, wff, bf, out, n);
    } else {
        fgm_scalar<<<(n + 255) / 256, 256, 0, stream>>>(
            coords, grid, W0, b0, Wh, bh, Wf, bf, out, n);
    }
}

// Round 9
// 58.829 us; speedup vs baseline: 1.1745x; 1.1745x over previous
//
#include <hip/hip_runtime.h>
#include <hip/hip_fp16.h>

#define NG 64
#define NVOX (NG*NG*NG)
#define NC 16
#define NHID 32
#define NL 10

typedef _Float16 half8 __attribute__((ext_vector_type(8)));
typedef __fp16   fp16x2 __attribute__((ext_vector_type(2)));
typedef float f32x16 __attribute__((ext_vector_type(16)));
typedef float f32x2 __attribute__((ext_vector_type(2)));

union U32H2 { unsigned u; fp16x2 h; __half2 hh; };
union U4H8  { uint4 u; half8 v; };

__device__ __forceinline__ unsigned pkrtz(float a, float b) {
    U32H2 t; t.h = __builtin_amdgcn_cvt_pkrtz(a, b); return t.u;
}
__device__ __forceinline__ half8 mk8(unsigned a, unsigned b, unsigned c, unsigned d) {
    union { unsigned u[4]; half8 v; } r;
    r.u[0] = a; r.u[1] = b; r.u[2] = c; r.u[3] = d; return r.v;
}
__device__ __forceinline__ f32x16 MF(half8 a, half8 b, f32x16 c) {
    return __builtin_amdgcn_mfma_f32_32x32x16_f16(a, b, c, 0, 0, 0);
}
// v_permlane32_swap_b32 a,b : a <- [a_lo | b_lo], b <- [a_hi | b_hi]
#define PSWAP(a, b) asm volatile("v_permlane32_swap_b32 %0, %1" : "+v"(a), "+v"(b))

// ---- workspace layout ----
#define GRID_BYTES ((size_t)NVOX * 16)               // 4 MiB fp8 grid (uint4/voxel)
#define A0F_OFF  GRID_BYTES                           // [5][64] uint4  layer-0 A frags
#define AHF_OFF  (A0F_OFF + (size_t)5 * 64 * 16)      // [6][64] uint4  hidden A frags
#define CBF_OFF  (AHF_OFF + (size_t)6 * 64 * 16)      // [12][64] float4 bias C frags
#define WFF_OFF  (CBF_OFF + (size_t)12 * 64 * 16)     // [4][64] float4  Wf frags
#define WS_NEED  (WFF_OFF + (size_t)4 * 64 * 16)

// Per-lane MFMA weight fragments (verified construction, R4/R8).
// x k-layout: k0,1=cx,cy k2=cz k3=1(bias) k4..63=PE k64..79=feats.
__device__ void pack_weights_lane(int lane,
    const float* __restrict__ W0, const float* __restrict__ b0,
    const float* __restrict__ Wh, const float* __restrict__ bh,
    const float* __restrict__ Wf,
    uint4* a0f, uint4* ahf, float4* cbf, float4* wff)
{
    const int H = lane >> 5, nn = lane & 31;
#pragma unroll
    for (int s = 0; s < 5; ++s) {
        float e[8];
#pragma unroll
        for (int i = 0; i < 8; ++i) {
            const int k0 = s * 16 + i;
            const float* q0 = (k0 == 3) ? (b0 + nn)
                             : (W0 + (k0 - (k0 >= 4 ? 1 : 0)) * NHID + nn);
            const float* q1 = W0 + (k0 + 8 - 1) * NHID + nn;   // k1>=8, never bias
            e[i] = *(H ? q1 : q0);
        }
        a0f[s * 64 + lane] = make_uint4(pkrtz(e[0], e[1]), pkrtz(e[2], e[3]),
                                        pkrtz(e[4], e[5]), pkrtz(e[6], e[7]));
    }
#pragma unroll
    for (int L = 0; L < 3; ++L) {
#pragma unroll
        for (int t = 0; t < 2; ++t) {
            float e[8];
#pragma unroll
            for (int i = 0; i < 8; ++i)
                e[i] = Wh[(L * NHID + t * 16 + H * 8 + i) * NHID + nn];
            ahf[(L * 2 + t) * 64 + lane] =
                make_uint4(pkrtz(e[0], e[1]), pkrtz(e[2], e[3]),
                           pkrtz(e[4], e[5]), pkrtz(e[6], e[7]));
        }
        float c[16];
#pragma unroll
        for (int r = 0; r < 16; ++r) {
            int nr = (r & 3) + 8 * (r >> 2) + 4 * H;
            c[r] = bh[L * NHID + nr];
        }
#pragma unroll
        for (int q = 0; q < 4; ++q)
            cbf[(L * 4 + q) * 64 + lane] =
                make_float4(c[4 * q], c[4 * q + 1], c[4 * q + 2], c[4 * q + 3]);
    }
    float w[16];
#pragma unroll
    for (int r = 0; r < 16; ++r) {
        int nr = (r & 3) + 8 * (r >> 2) + 4 * H;
        w[r] = Wf[nr];
    }
#pragma unroll
    for (int q = 0; q < 4; ++q)
        wff[q * 64 + lane] = make_float4(w[4 * q], w[4 * q + 1], w[4 * q + 2], w[4 * q + 3]);
}

// ---- pass 1: grid f32 (C,D,H,W) -> voxel-major fp8 e4m3; block 0 packs weights ----
__global__ __launch_bounds__(256) void prep_kernel(
    const float* __restrict__ in, uint4* __restrict__ gout,
    const float* __restrict__ W0, const float* __restrict__ b0,
    const float* __restrict__ Wh, const float* __restrict__ bh,
    const float* __restrict__ Wf,
    uint4* a0f, uint4* ahf, float4* cbf, float4* wff)
{
    int v = blockIdx.x * 256 + threadIdx.x;
    if (v < NVOX) {
        unsigned o[4];
#pragma unroll
        for (int c = 0; c < 4; ++c) {
            float f0 = in[(4 * c + 0) * NVOX + v];
            float f1 = in[(4 * c + 1) * NVOX + v];
            float f2 = in[(4 * c + 2) * NVOX + v];
            float f3 = in[(4 * c + 3) * NVOX + v];
            int w = 0;
            w = __builtin_amdgcn_cvt_pk_fp8_f32(f0, f1, w, false);
            w = __builtin_amdgcn_cvt_pk_fp8_f32(f2, f3, w, true);
            o[c] = (unsigned)w;
        }
        gout[v] = make_uint4(o[0], o[1], o[2], o[3]);
    }
    if (blockIdx.x == 0 && threadIdx.x < 64)
        pack_weights_lane(threadIdx.x, W0, b0, Wh, bh, Wf, a0f, ahf, cbf, wff);
}

// ---- pass 2: fused grid-sample + PE + 4-layer MLP, f16 MFMA, zero LDS ----
// (256,4): VGPR cap 128 so the 8 corner loads + fv stay in flight (R8 lesson).
__global__ __launch_bounds__(256, 4) void fgm_mfma(
    const float* __restrict__ coords, const uint4* __restrict__ grid8,
    const uint4* __restrict__ a0f, const uint4* __restrict__ ahf,
    const float4* __restrict__ cbf, const float4* __restrict__ wff,
    const float* __restrict__ bf,
    float* __restrict__ out, int n)
{
    const int lane = threadIdx.x & 63;
    const int wid  = threadIdx.x >> 6;
    const int base = blockIdx.x * 256 + wid * 64;
    if (base >= n) return;
    const int p  = base + lane;
    const int pc = min(p, n - 1);
    const int H  = lane >> 5;

    // hoist layer-0 A-frag loads: in flight during gather address calc
    U4H8 af0, af1, af2, af3, af4;
    af0.u = a0f[0 * 64 + lane];
    af1.u = a0f[1 * 64 + lane];
    af2.u = a0f[2 * 64 + lane];
    af3.u = a0f[3 * 64 + lane];
    af4.u = a0f[4 * 64 + lane];

    float cx = coords[3 * pc + 0], cy = coords[3 * pc + 1], cz = coords[3 * pc + 2];

    // ---- trilinear grid sample, fp8 grid -> f32 accumulate ----
    float fx = (cx + 1.0f) * (NG * 0.5f) - 0.5f;
    float fy = (cy + 1.0f) * (NG * 0.5f) - 0.5f;
    float fz = (cz + 1.0f) * (NG * 0.5f) - 0.5f;
    float flx = floorf(fx), fly = floorf(fy), flz = floorf(fz);
    float wx = fx - flx, wy = fy - fly, wz = fz - flz;
    int ix0 = (int)flx, iy0 = (int)fly, iz0 = (int)flz;
    float wxs[2] = {1.0f - wx, wx}, wys[2] = {1.0f - wy, wy}, wzs[2] = {1.0f - wz, wz};

    float fv[NC];
#pragma unroll
    for (int c = 0; c < NC; ++c) fv[c] = 0.0f;

#pragma unroll
    for (int dz = 0; dz < 2; ++dz) {
        int zi = iz0 + dz; bool vz = (zi >= 0) && (zi < NG);
        int zc = min(max(zi, 0), NG - 1);
#pragma unroll
        for (int dy = 0; dy < 2; ++dy) {
            int yi = iy0 + dy; bool vy = (yi >= 0) && (yi < NG);
            int yc = min(max(yi, 0), NG - 1);
#pragma unroll
            for (int dx = 0; dx < 2; ++dx) {
                int xi = ix0 + dx; bool vx = (xi >= 0) && (xi < NG);
                int xc = min(max(xi, 0), NG - 1);
                float w = wzs[dz] * wys[dy] * wxs[dx];
                w = (vx && vy && vz) ? w : 0.0f;
                uint4 q = grid8[((zc * NG) + yc) * NG + xc];
                f32x2 d;
                d = __builtin_amdgcn_cvt_pk_f32_fp8((int)q.x, false);
                fv[0]  = fmaf(w, d.x, fv[0]);  fv[1]  = fmaf(w, d.y, fv[1]);
                d = __builtin_amdgcn_cvt_pk_f32_fp8((int)q.x, true);
                fv[2]  = fmaf(w, d.x, fv[2]);  fv[3]  = fmaf(w, d.y, fv[3]);
                d = __builtin_amdgcn_cvt_pk_f32_fp8((int)q.y, false);
                fv[4]  = fmaf(w, d.x, fv[4]);  fv[5]  = fmaf(w, d.y, fv[5]);
                d = __builtin_amdgcn_cvt_pk_f32_fp8((int)q.y, true);
                fv[6]  = fmaf(w, d.x, fv[6]);  fv[7]  = fmaf(w, d.y, fv[7]);
                d = __builtin_amdgcn_cvt_pk_f32_fp8((int)q.z, false);
                fv[8]  = fmaf(w, d.x, fv[8]);  fv[9]  = fmaf(w, d.y, fv[9]);
                d = __builtin_amdgcn_cvt_pk_f32_fp8((int)q.z, true);
                fv[10] = fmaf(w, d.x, fv[10]); fv[11] = fmaf(w, d.y, fv[11]);
                d = __builtin_amdgcn_cvt_pk_f32_fp8((int)q.w, false);
                fv[12] = fmaf(w, d.x, fv[12]); fv[13] = fmaf(w, d.y, fv[13]);
                d = __builtin_amdgcn_cvt_pk_f32_fp8((int)q.w, true);
                fv[14] = fmaf(w, d.x, fv[14]); fv[15] = fmaf(w, d.y, fv[15]);
            }
        }
    }

    // ---- x (f16 pairs): PE via angle-doubling recurrence ----
    // sincos at f=1 only; (s,c) -> (2sc, 1-2s^2) per octave (exact angle, no
    // range-reduction error; drift ~2^l*eps << f16 rounding).
    unsigned xr[40];
    xr[0] = pkrtz(cx, cy);
    xr[1] = pkrtz(cz, 1.0f);      // k=3: bias row input = 1
    {
        float sx, cxc, sy, cyc, sz, czc;
        __sincosf(cx, &sx, &cxc);
        __sincosf(cy, &sy, &cyc);
        __sincosf(cz, &sz, &czc);
#pragma unroll
        for (int l0 = 0; l0 < NL; ++l0) {
            xr[2 + 3 * l0 + 0] = pkrtz(sx, sy);
            xr[2 + 3 * l0 + 1] = pkrtz(sz, cxc);
            xr[2 + 3 * l0 + 2] = pkrtz(cyc, czc);
            if (l0 < NL - 1) {
                float t, u;
                t = sx * cxc; u = sx * sx; sx = t + t; cxc = fmaf(-2.0f, u, 1.0f);
                t = sy * cyc; u = sy * sy; sy = t + t; cyc = fmaf(-2.0f, u, 1.0f);
                t = sz * czc; u = sz * sz; sz = t + t; czc = fmaf(-2.0f, u, 1.0f);
            }
        }
    }
#pragma unroll
    for (int j = 0; j < 8; ++j)
        xr[32 + j] = pkrtz(fv[2 * j], fv[2 * j + 1]);

    // ---- layer-0 B-fragments via permlane32_swap (in place on xr) ----
#pragma unroll
    for (int s = 0; s < 5; ++s) {
        PSWAP(xr[8 * s + 0], xr[8 * s + 4]);
        PSWAP(xr[8 * s + 1], xr[8 * s + 5]);
        PSWAP(xr[8 * s + 2], xr[8 * s + 6]);
        PSWAP(xr[8 * s + 3], xr[8 * s + 7]);
    }

    // ---- layer 0: 5 K-slices x 2 tiles, prepacked A frags ----
    f32x16 acc0, acc1;
#pragma unroll
    for (int r = 0; r < 16; ++r) { acc0[r] = 0.0f; acc1[r] = 0.0f; }
    acc0 = MF(af0.v, mk8(xr[0], xr[1], xr[2], xr[3]), acc0);
    acc1 = MF(af0.v, mk8(xr[4], xr[5], xr[6], xr[7]), acc1);
    acc0 = MF(af1.v, mk8(xr[8], xr[9], xr[10], xr[11]), acc0);
    acc1 = MF(af1.v, mk8(xr[12], xr[13], xr[14], xr[15]), acc1);
    acc0 = MF(af2.v, mk8(xr[16], xr[17], xr[18], xr[19]), acc0);
    acc1 = MF(af2.v, mk8(xr[20], xr[21], xr[22], xr[23]), acc1);
    acc0 = MF(af3.v, mk8(xr[24], xr[25], xr[26], xr[27]), acc0);
    acc1 = MF(af3.v, mk8(xr[28], xr[29], xr[30], xr[31]), acc1);
    acc0 = MF(af4.v, mk8(xr[32], xr[33], xr[34], xr[35]), acc0);
    acc1 = MF(af4.v, mk8(xr[36], xr[37], xr[38], xr[39]), acc1);

    // ---- hidden layers: snake -> f16 pairs -> permlane B-frags -> MFMA ----
#pragma unroll
    for (int L = 0; L < 3; ++L) {
        unsigned w0a[8], w1a[8];
#pragma unroll
        for (int j = 0; j < 8; ++j) {
            {
                float x0 = acc0[2 * j], x1 = acc0[2 * j + 1];
                float s0 = __sinf(x0), s1 = __sinf(x1);
                w0a[j] = pkrtz(fmaf(0.5f, x0, s0 * s0), fmaf(0.5f, x1, s1 * s1));
            }
            {
                float x0 = acc1[2 * j], x1 = acc1[2 * j + 1];
                float s0 = __sinf(x0), s1 = __sinf(x1);
                w1a[j] = pkrtz(fmaf(0.5f, x0, s0 * s0), fmaf(0.5f, x1, s1 * s1));
            }
        }
        PSWAP(w0a[0], w0a[2]); PSWAP(w0a[1], w0a[3]);
        PSWAP(w0a[4], w0a[6]); PSWAP(w0a[5], w0a[7]);
        PSWAP(w1a[0], w1a[2]); PSWAP(w1a[1], w1a[3]);
        PSWAP(w1a[4], w1a[6]); PSWAP(w1a[5], w1a[7]);

        float4 c0 = cbf[(L * 4 + 0) * 64 + lane];
        float4 c1 = cbf[(L * 4 + 1) * 64 + lane];
        float4 c2 = cbf[(L * 4 + 2) * 64 + lane];
        float4 c3 = cbf[(L * 4 + 3) * 64 + lane];
        f32x16 cb;
        cb[0]  = c0.x; cb[1]  = c0.y; cb[2]  = c0.z; cb[3]  = c0.w;
        cb[4]  = c1.x; cb[5]  = c1.y; cb[6]  = c1.z; cb[7]  = c1.w;
        cb[8]  = c2.x; cb[9]  = c2.y; cb[10] = c2.z; cb[11] = c2.w;
        cb[12] = c3.x; cb[13] = c3.y; cb[14] = c3.z; cb[15] = c3.w;

        U4H8 A0, A1;
        A0.u = ahf[(L * 2 + 0) * 64 + lane];
        A1.u = ahf[(L * 2 + 1) * 64 + lane];

        acc0 = MF(A1.v, mk8(w0a[4], w0a[5], w0a[6], w0a[7]),
                  MF(A0.v, mk8(w0a[0], w0a[1], w0a[2], w0a[3]), cb));
        acc1 = MF(A1.v, mk8(w1a[4], w1a[5], w1a[6], w1a[7]),
                  MF(A0.v, mk8(w1a[0], w1a[1], w1a[2], w1a[3]), cb));
    }

    // ---- final layer: snake -> dot(Wf) -> cross-half reduce ----
    float4 w0v = wff[0 * 64 + lane], w1v = wff[1 * 64 + lane];
    float4 w2v = wff[2 * 64 + lane], w3v = wff[3 * 64 + lane];
    float wfv[16] = {w0v.x, w0v.y, w0v.z, w0v.w, w1v.x, w1v.y, w1v.z, w1v.w,
                     w2v.x, w2v.y, w2v.z, w2v.w, w3v.x, w3v.y, w3v.z, w3v.w};
    float t0 = 0.0f, t1 = 0.0f;
#pragma unroll
    for (int r = 0; r < 16; ++r) {
        float wf = wfv[r];
        { float x = acc0[r]; float s = __sinf(x); t0 = fmaf(fmaf(0.5f, x, s * s), wf, t0); }
        { float x = acc1[r]; float s = __sinf(x); t1 = fmaf(fmaf(0.5f, x, s * s), wf, t1); }
    }
    t0 += __shfl_xor(t0, 32);
    t1 += __shfl_xor(t1, 32);
    float res = (H ? t1 : t0) + bf[0];
    if (p < n) out[p] = res;
}

// ---- fallback (ws too small): scalar fp32 path, channels-first grid ----
__global__ __launch_bounds__(256) void fgm_scalar(
    const float* __restrict__ coords, const float* __restrict__ grid,
    const float* __restrict__ W0, const float* __restrict__ b0,
    const float* __restrict__ Wh, const float* __restrict__ bh,
    const float* __restrict__ Wf, const float* __restrict__ bf,
    float* __restrict__ out, int n)
{
    int i = blockIdx.x * blockDim.x + threadIdx.x;
    if (i >= n) return;
    float cx = coords[3 * i + 0], cy = coords[3 * i + 1], cz = coords[3 * i + 2];
    float fx = (cx + 1.0f) * (NG * 0.5f) - 0.5f;
    float fy = (cy + 1.0f) * (NG * 0.5f) - 0.5f;
    float fz = (cz + 1.0f) * (NG * 0.5f) - 0.5f;
    float flx = floorf(fx), fly = floorf(fy), flz = floorf(fz);
    float wx = fx - flx, wy = fy - fly, wz = fz - flz;
    int ix0 = (int)flx, iy0 = (int)fly, iz0 = (int)flz;
    float fv[NC];
#pragma unroll
    for (int c = 0; c < NC; ++c) fv[c] = 0.0f;
    float wxs[2] = {1.0f - wx, wx}, wys[2] = {1.0f - wy, wy}, wzs[2] = {1.0f - wz, wz};
#pragma unroll
    for (int dz = 0; dz < 2; ++dz) {
        int zi = iz0 + dz; bool vz = (zi >= 0) && (zi < NG);
        int zc = min(max(zi, 0), NG - 1);
#pragma unroll
        for (int dy = 0; dy < 2; ++dy) {
            int yi = iy0 + dy; bool vy = (yi >= 0) && (yi < NG);
            int yc = min(max(yi, 0), NG - 1);
#pragma unroll
            for (int dx = 0; dx < 2; ++dx) {
                int xi = ix0 + dx; bool vx = (xi >= 0) && (xi < NG);
                int xc = min(max(xi, 0), NG - 1);
                float w = wzs[dz] * wys[dy] * wxs[dx];
                w = (vx && vy && vz) ? w : 0.0f;
                int off = ((zc * NG) + yc) * NG + xc;
#pragma unroll
                for (int c = 0; c < NC; ++c)
                    fv[c] = fmaf(w, grid[c * NVOX + off], fv[c]);
            }
        }
    }
    float h[NHID];
#pragma unroll
    for (int j = 0; j < NHID; ++j) h[j] = b0[j];
#pragma unroll
    for (int j = 0; j < NHID; ++j) h[j] = fmaf(cx, W0[0 * NHID + j], h[j]);
#pragma unroll
    for (int j = 0; j < NHID; ++j) h[j] = fmaf(cy, W0[1 * NHID + j], h[j]);
#pragma unroll
    for (int j = 0; j < NHID; ++j) h[j] = fmaf(cz, W0[2 * NHID + j], h[j]);
#pragma unroll
    for (int l = 0; l < NL; ++l) {
        float fs = (float)(1 << l);
        float sv[6];
        sv[0] = __sinf(cx * fs); sv[1] = __sinf(cy * fs); sv[2] = __sinf(cz * fs);
        sv[3] = __cosf(cx * fs); sv[4] = __cosf(cy * fs); sv[5] = __cosf(cz * fs);
#pragma unroll
        for (int r = 0; r < 6; ++r) {
            const float* wr = W0 + (size_t)(3 + 6 * l + r) * NHID;
            float a = sv[r];
#pragma unroll
            for (int j = 0; j < NHID; ++j) h[j] = fmaf(a, wr[j], h[j]);
        }
    }
#pragma unroll
    for (int r = 0; r < NC; ++r) {
        const float* wr = W0 + (size_t)(3 + 6 * NL + r) * NHID;
        float a = fv[r];
#pragma unroll
        for (int j = 0; j < NHID; ++j) h[j] = fmaf(a, wr[j], h[j]);
    }
    float act[NHID];
#pragma unroll
    for (int layer = 0; layer < 3; ++layer) {
#pragma unroll
        for (int j = 0; j < NHID; ++j) {
            float s = __sinf(h[j]);
            act[j] = fmaf(0.5f, h[j], s * s);
        }
#pragma unroll
        for (int j = 0; j < NHID; ++j) h[j] = bh[layer * NHID + j];
#pragma unroll
        for (int r = 0; r < NHID; ++r) {
            const float* wr = Wh + (size_t)(layer * NHID + r) * NHID;
            float a = act[r];
#pragma unroll
            for (int j = 0; j < NHID; ++j) h[j] = fmaf(a, wr[j], h[j]);
        }
    }
    float acc = bf[0];
#pragma unroll
    for (int j = 0; j < NHID; ++j) {
        float s = __sinf(h[j]);
        acc = fmaf(fmaf(0.5f, h[j], s * s), Wf[j], acc);
    }
    out[i] = acc;
}

extern "C" void kernel_launch(void* const* d_in, const int* in_sizes, int n_in,
                              void* d_out, int out_size, void* d_ws, size_t ws_size,
                              hipStream_t stream)
{
    const float* coords = (const float*)d_in[0];
    const float* grid   = (const float*)d_in[1];
    const float* W0     = (const float*)d_in[2];
    const float* b0     = (const float*)d_in[3];
    const float* Wh     = (const float*)d_in[4];
    const float* bh     = (const float*)d_in[5];
    const float* Wf     = (const float*)d_in[6];
    const float* bf     = (const float*)d_in[7];
    float* out = (float*)d_out;
    int n = in_sizes[0] / 3;

    if (ws_size >= WS_NEED) {
        char* ws = (char*)d_ws;
        uint4*  g8  = (uint4*)ws;
        uint4*  a0f = (uint4*)(ws + A0F_OFF);
        uint4*  ahf = (uint4*)(ws + AHF_OFF);
        float4* cbf = (float4*)(ws + CBF_OFF);
        float4* wff = (float4*)(ws + WFF_OFF);
        prep_kernel<<<(NVOX + 255) / 256, 256, 0, stream>>>(
            grid, g8, W0, b0, Wh, bh, Wf, a0f, ahf, cbf, wff);
        fgm_mfma<<<(n + 255) / 256, 256, 0, stream>>>(
            coords, g8, a0f, ahf, cbf, wff, bf, out, n);
    } else {
        fgm_scalar<<<(n + 255) / 256, 256, 0, stream>>>(
            coords, grid, W0, b0, Wh, bh, Wf, bf, out, n);
    }
}